// Round 14
// baseline (155.585 us; speedup 1.0000x reference)
//
#include <hip/hip_runtime.h>
#include <stdint.h>

#define NA 98304
#define NT 1024
#define NC 21
#define ACH 192          // anchor chunks of 512 (2 anchors per thread)
#define TCH 16           // target chunks of 64
#define NBLK (ACH * TCH) // 3072
#define HI_MIN 0xBF000000u   // min high-word of a valid key (iou>=0.5, bias bit)

// ws layout:
//   [0]     int   done2                 (zeroed by memset)
//   [64]    int   done_ac[192]          (768 B, zeroed by memset)
//   [1024]  float f0_part[NBLK]         (12 KB, unique-slot atomic stores)
//   [13312] float corr_part[192]        (768 B, unique-slot)
//   [14080] int   npos_part[192]        (768 B, unique-slot)
//   [16384] u64   tkeys[NT]             (8 KB, NOT zeroed: poison-proof keys)
//   [24576] u64   akeys[NA]             (768 KB, NOT zeroed)
// memset covers only [0, 1024)

__device__ __forceinline__ float f0(float x) {   // focal, target=0
    const float ax = fabsf(x);
    const float u  = __expf(-ax);
    const float ce = fmaxf(x, 0.f) + __logf(1.f + u);
    const float p  = (x >= 0.f ? 1.f : u) / (1.f + u);
    return 0.75f * p * p * ce;
}
__device__ __forceinline__ float f1(float x) {   // focal, target=1
    const float ax = fabsf(x);
    const float u  = __expf(-ax);
    const float ce = fmaxf(x, 0.f) - x + __logf(1.f + u);
    const float p  = (x >= 0.f ? 1.f : u) / (1.f + u);
    const float q  = 1.f - p;
    return 0.25f * q * q * ce;
}
__device__ __forceinline__ unsigned long long mk_key(float iou, unsigned int idx) {
    // bias bit: valid keys beat 0xAA-poison and 0 under unsigned atomicMax;
    // iou ordering preserved; low word 0xFFFFFFFF-idx -> smaller index wins ties.
    return ((unsigned long long)(__float_as_uint(iou) | 0x80000000u) << 32) |
           (unsigned long long)(0xFFFFFFFFu - idx);
}
__device__ __forceinline__ float smooth_l1(float d) {
    const float ad = fabsf(d);
    return (ad < 1.f) ? 0.5f * d * d : ad - 0.5f;
}
__device__ __forceinline__ unsigned long long aload64(const unsigned long long* p) {
    return __hip_atomic_load(p, __ATOMIC_RELAXED, __HIP_MEMORY_SCOPE_AGENT);
}
__device__ __forceinline__ float aloadf(const float* p) {
    return __hip_atomic_load(p, __ATOMIC_RELAXED, __HIP_MEMORY_SCOPE_AGENT);
}
__device__ __forceinline__ int aloadi(const int* p) {
    return __hip_atomic_load(p, __ATOMIC_RELAXED, __HIP_MEMORY_SCOPE_AGENT);
}

__global__ __launch_bounds__(256) void k_all(
    const float* __restrict__ preds,
    const float4* __restrict__ preds4,
    const int* __restrict__ tlabels,
    const float4* __restrict__ anchors,
    const float4* __restrict__ tboxes,
    const float4* __restrict__ bpreds,
    unsigned long long* __restrict__ akeys,
    unsigned long long* __restrict__ tkeys,
    float* __restrict__ f0_part,
    float* __restrict__ corr_part,
    int* __restrict__ npos_part,
    int* __restrict__ done_ac,
    int* __restrict__ done2,
    float* __restrict__ out)
{
    __shared__ float4 s_t[64];
    __shared__ float  s_sa[64];
    __shared__ unsigned long long s_tk[64];
    __shared__ float s_f[4];
    __shared__ int   s_last, s_fin;
    __shared__ float s_a[4];
    __shared__ int   s_c[4];
    __shared__ double s_d[4];
    __shared__ int    s_i[4];
    __shared__ float  s_s[4], s_m[4];

    const int tid   = threadIdx.x;
    const int ac    = blockIdx.x;
    const int L     = blockIdx.y * ACH + ac;
    const int tbase = blockIdx.y * 64;
    const int a0    = ac * 512 + tid;
    const int a1    = a0 + 256;
    const int lane  = tid & 63, wid = tid >> 6;

    // ================= PHASE A: match + f0 slice ==============================
    if (tid < 64) {
        const float4 tb = tboxes[tbase + tid];
        s_t[tid]  = tb;
        s_sa[tid] = (tb.z - tb.x) * (tb.w - tb.y);   // area in LDS: 3 VALU/iter off
        s_tk[tid] = 0ull;
    }
    const float4 A0 = anchors[a0];
    const float4 A1 = anchors[a1];

    // f0 over this block's contiguous 168-float4 slice of preds (no match dep)
    float facc = 0.f;
    if (tid < 168) {
        const float4 v0 = preds4[L * 168 + tid];
        facc = (f0(v0.x) + f0(v0.y)) + (f0(v0.z) + f0(v0.w));
    }
    __syncthreads();

    const float ar0 = (A0.z - A0.x) * (A0.w - A0.y);
    const float ar1 = (A1.z - A1.x) * (A1.w - A1.y);

    float b0 = 0.f, b1 = 0.f;
    int   i0 = -1,  i1 = -1;

    #pragma unroll 4
    for (int t = 0; t < 64; ++t) {
        const float4 tb = s_t[t];          // broadcast b128, shared by 2 anchors
        const float  sa = s_sa[t];         // broadcast b32
        {
            const float lx = fmaxf(A0.x, tb.x);
            const float ly = fmaxf(A0.y, tb.y);
            const float rx = fminf(A0.z, tb.z);
            const float ry = fminf(A0.w, tb.w);
            const float w  = fmaxf(rx - lx, 0.f);
            const float h  = fmaxf(ry - ly, 0.f);
            const float inter = w * h;
            const float uni = (ar0 + sa) - inter;
            if (__builtin_expect(inter + inter >= uni, 0)) {
                const float iou = inter / uni;   // exact div = reference rounding
                if (iou > b0) { b0 = iou; i0 = t; }
                atomicMax(&s_tk[t], mk_key(iou, (unsigned int)a0));
            }
        }
        {
            const float lx = fmaxf(A1.x, tb.x);
            const float ly = fmaxf(A1.y, tb.y);
            const float rx = fminf(A1.z, tb.z);
            const float ry = fminf(A1.w, tb.w);
            const float w  = fmaxf(rx - lx, 0.f);
            const float h  = fmaxf(ry - ly, 0.f);
            const float inter = w * h;
            const float uni = (ar1 + sa) - inter;
            if (__builtin_expect(inter + inter >= uni, 0)) {
                const float iou = inter / uni;
                if (iou > b1) { b1 = iou; i1 = t; }
                atomicMax(&s_tk[t], mk_key(iou, (unsigned int)a1));
            }
        }
    }

    // fire-and-forget flushes ONLY (no return-value dependence — R9 lesson)
    if (i0 >= 0) atomicMax(&akeys[a0], mk_key(b0, (unsigned int)(tbase + i0)));
    if (i1 >= 0) atomicMax(&akeys[a1], mk_key(b1, (unsigned int)(tbase + i1)));

    for (int o = 32; o > 0; o >>= 1) facc += __shfl_down(facc, o);
    if (lane == 0) s_f[wid] = facc;

    __syncthreads();
    if (tid < 64) {
        const unsigned long long tk = s_tk[tid];
        if (tk != 0ull) atomicMax(&tkeys[tbase + tid], tk);
    }
    if (tid == 0)   // unique slot, agent-scope store (L1-bypass)
        __hip_atomic_store(&f0_part[L], s_f[0] + s_f[1] + s_f[2] + s_f[3],
                           __ATOMIC_RELAXED, __HIP_MEMORY_SCOPE_AGENT);

    // barrier drains vmcnt: this block's key flushes complete before counter bump
    __syncthreads();
    if (tid == 0) {
        __threadfence();
        s_last = (atomicAdd(&done_ac[ac], 1) == TCH - 1);
    }
    __syncthreads();
    if (!s_last) return;
    __builtin_amdgcn_fence(__ATOMIC_ACQUIRE, "agent");   // L1 invalidate

    // ============ PHASE B (192 completers): corrections for 512 anchors =======
    float acc = 0.f;
    int   cnt = 0;
    {
        const unsigned long long k = aload64(&akeys[a0]);   // cheap coherent load
        if ((unsigned int)(k >> 32) >= HI_MIN) {
            cnt = 1;
            const int lab = tlabels[0xFFFFFFFFu - (unsigned int)k];
            const float x = preds[a0 * NC + lab];
            acc += f1(x) - f0(x);
        }
    }
    {
        const unsigned long long k = aload64(&akeys[a1]);
        if ((unsigned int)(k >> 32) >= HI_MIN) {
            cnt += 1;
            const int lab = tlabels[0xFFFFFFFFu - (unsigned int)k];
            const float x = preds[a1 * NC + lab];
            acc += f1(x) - f0(x);
        }
    }
    // fold the 16 f0 slices of this ac (written + fenced before done_ac bumps)
    if (tid < TCH) acc += aloadf(&f0_part[ac + tid * ACH]);

    for (int o = 32; o > 0; o >>= 1) {
        acc += __shfl_down(acc, o);
        cnt += __shfl_down(cnt, o);
    }
    if (lane == 0) { s_a[wid] = acc; s_c[wid] = cnt; }
    __syncthreads();
    if (tid == 0) {
        __hip_atomic_store(&corr_part[ac], s_a[0] + s_a[1] + s_a[2] + s_a[3],
                           __ATOMIC_RELAXED, __HIP_MEMORY_SCOPE_AGENT);
        __hip_atomic_store(&npos_part[ac], s_c[0] + s_c[1] + s_c[2] + s_c[3],
                           __ATOMIC_RELAXED, __HIP_MEMORY_SCOPE_AGENT);
        __threadfence();
        s_fin = (atomicAdd(done2, 1) == ACH - 1);
    }
    __syncthreads();
    if (!s_fin) return;
    __builtin_amdgcn_fence(__ATOMIC_ACQUIRE, "agent");

    // ============ PHASE C (last completer): regression + combine ==============
    double cl = 0.0;
    int    np = 0;
    if (tid < ACH) {
        cl = (double)aloadf(&corr_part[tid]);
        np = aloadi(&npos_part[tid]);
    }
    float s = 0.f, m = 0.f;
    #pragma unroll
    for (int j = 0; j < 4; ++j) {
        const int t = tid + 256 * j;
        const unsigned long long key = aload64(&tkeys[t]);
        if ((unsigned int)(key >> 32) >= HI_MIN) {
            const unsigned int ga = 0xFFFFFFFFu - (unsigned int)key;
            const float4 tb  = tboxes[t];
            const float4 abx = anchors[ga];
            const float4 pb  = bpreds[ga];
            const float bw = tb.z - tb.x, bh = tb.w - tb.y;
            const float bcx = tb.x + 0.5f * bw, bcy = tb.y + 0.5f * bh;
            const float aw = abx.z - abx.x, ah = abx.w - abx.y;
            const float acx = abx.x + 0.5f * aw, acy = abx.y + 0.5f * ah;
            const float tx = (bcx - acx) / aw;
            const float ty = (bcy - acy) / ah;
            const float tw = logf(fmaxf(bw, 1e-8f) / aw);
            const float th = logf(fmaxf(bh, 1e-8f) / ah);
            s += smooth_l1(pb.x - tx) + smooth_l1(pb.y - ty) +
                 smooth_l1(pb.z - tw) + smooth_l1(pb.w - th);
            m += 1.f;
        }
    }
    for (int o = 32; o > 0; o >>= 1) {
        cl += __shfl_down(cl, o);
        np += __shfl_down(np, o);
        s  += __shfl_down(s, o);
        m  += __shfl_down(m, o);
    }
    __syncthreads();
    if (lane == 0) { s_d[wid] = cl; s_i[wid] = np; s_s[wid] = s; s_m[wid] = m; }
    __syncthreads();
    if (tid == 0) {
        const double cls_sum = s_d[0] + s_d[1] + s_d[2] + s_d[3];
        const int    npos    = s_i[0] + s_i[1] + s_i[2] + s_i[3];
        const float  rs      = s_s[0] + s_s[1] + s_s[2] + s_s[3];
        const float  rm      = s_m[0] + s_m[1] + s_m[2] + s_m[3];
        const float cls = (float)(cls_sum / (double)npos);
        const float reg = rs / (fmaxf(rm, 1.f) * 4.f);
        out[0] = cls + reg;
        out[1] = cls;
        out[2] = reg;
    }
}

extern "C" void kernel_launch(void* const* d_in, const int* in_sizes, int n_in,
                              void* d_out, int out_size, void* d_ws, size_t ws_size,
                              hipStream_t stream) {
    const float*  preds   = (const float*)d_in[0];
    const float4* preds4  = (const float4*)d_in[0];
    const float4* bpreds  = (const float4*)d_in[1];
    const float4* anchors = (const float4*)d_in[2];
    const float4* tboxes  = (const float4*)d_in[3];
    const int*    tlabels = (const int*)d_in[4];

    char* ws = (char*)d_ws;
    int*    done2     = (int*)(ws + 0);
    int*    done_ac   = (int*)(ws + 64);
    float*  f0_part   = (float*)(ws + 1024);
    float*  corr_part = (float*)(ws + 13312);
    int*    npos_part = (int*)(ws + 14080);
    unsigned long long* tkeys = (unsigned long long*)(ws + 16384);
    unsigned long long* akeys = (unsigned long long*)(ws + 24576);

    // only the done counters need zeroing (everything else unique-slot/poison-proof)
    hipMemsetAsync(d_ws, 0, 1024, stream);

    k_all<<<dim3(ACH, TCH), 256, 0, stream>>>(
        preds, preds4, tlabels, anchors, tboxes, bpreds,
        akeys, tkeys, f0_part, corr_part, npos_part,
        done_ac, done2, (float*)d_out);
}

// Round 15
// 132.219 us; speedup vs baseline: 1.1767x; 1.1767x over previous
//
#include <hip/hip_runtime.h>
#include <stdint.h>

#define NA 98304
#define NT 1024
#define NC 21
#define ACH 96           // anchor chunks of 1024 (4 anchors per thread)
#define TCH 16           // target chunks of 64 (= bitmask width)
#define NBLK (ACH * TCH) // 1536
#define HI_MIN 0xBF000000u   // min high-word of a valid key (iou>=0.5, bias bit)

// ws layout:
//   [0]     int   done2               (zeroed by memset)
//   [64]    int   done_ac[96]         (384 B, zeroed by memset)
//   [1024]  float f0_part[NBLK]       (6 KB, unique-slot atomic stores)
//   [8192]  float corr_part[96]       (384 B, unique-slot)
//   [8704]  int   npos_part[96]       (384 B, unique-slot)
//   [12288] u64   tkeys[NT]           (8 KB, NOT zeroed: poison-proof keys)
//   [24576] u64   akeys[NA]           (768 KB, NOT zeroed)
// memset covers only [0, 1024)

__device__ __forceinline__ float f0(float x) {   // focal, target=0
    const float ax = fabsf(x);
    const float u  = __expf(-ax);
    const float ce = fmaxf(x, 0.f) + __logf(1.f + u);
    const float p  = (x >= 0.f ? 1.f : u) / (1.f + u);
    return 0.75f * p * p * ce;
}
__device__ __forceinline__ float f1(float x) {   // focal, target=1
    const float ax = fabsf(x);
    const float u  = __expf(-ax);
    const float ce = fmaxf(x, 0.f) - x + __logf(1.f + u);
    const float p  = (x >= 0.f ? 1.f : u) / (1.f + u);
    const float q  = 1.f - p;
    return 0.25f * q * q * ce;
}
__device__ __forceinline__ unsigned long long mk_key(float iou, unsigned int idx) {
    // bias bit: valid keys beat 0xAA-poison and 0 under unsigned atomicMax;
    // iou ordering preserved; low word 0xFFFFFFFF-idx -> smaller index wins ties.
    return ((unsigned long long)(__float_as_uint(iou) | 0x80000000u) << 32) |
           (unsigned long long)(0xFFFFFFFFu - idx);
}
__device__ __forceinline__ float smooth_l1(float d) {
    const float ad = fabsf(d);
    return (ad < 1.f) ? 0.5f * d * d : ad - 0.5f;
}
__device__ __forceinline__ unsigned long long aload64(const unsigned long long* p) {
    return __hip_atomic_load(p, __ATOMIC_RELAXED, __HIP_MEMORY_SCOPE_AGENT);
}
__device__ __forceinline__ float aloadf(const float* p) {
    return __hip_atomic_load(p, __ATOMIC_RELAXED, __HIP_MEMORY_SCOPE_AGENT);
}
__device__ __forceinline__ int aloadi(const int* p) {
    return __hip_atomic_load(p, __ATOMIC_RELAXED, __HIP_MEMORY_SCOPE_AGENT);
}

__global__ __launch_bounds__(256) void k_all(
    const float* __restrict__ preds,
    const float4* __restrict__ preds4,
    const int* __restrict__ tlabels,
    const float4* __restrict__ anchors,
    const float4* __restrict__ tboxes,
    const float4* __restrict__ bpreds,
    unsigned long long* __restrict__ akeys,
    unsigned long long* __restrict__ tkeys,
    float* __restrict__ f0_part,
    float* __restrict__ corr_part,
    int* __restrict__ npos_part,
    int* __restrict__ done_ac,
    int* __restrict__ done2,
    float* __restrict__ out)
{
    __shared__ float4 s_t[64];
    __shared__ float  s_sa[64];
    __shared__ unsigned long long s_tk[64];
    __shared__ float s_f[4];
    __shared__ int   s_last, s_fin;
    __shared__ float s_a[4];
    __shared__ int   s_c[4];
    __shared__ double s_d[4];
    __shared__ int    s_i[4];
    __shared__ float  s_s[4], s_m[4];

    const int tid   = threadIdx.x;
    const int ac    = blockIdx.x;
    const int L     = blockIdx.y * ACH + ac;
    const int tbase = blockIdx.y * 64;
    const int a0    = ac * 1024 + tid;   // anchors a0, +256, +512, +768
    const int lane  = tid & 63, wid = tid >> 6;

    // ================= PHASE A: branchless hit-mask match + f0 slice ==========
    if (tid < 64) {
        const float4 tb = tboxes[tbase + tid];
        s_t[tid]  = tb;
        s_sa[tid] = (tb.z - tb.x) * (tb.w - tb.y);
        s_tk[tid] = 0ull;
    }
    const float4 A0 = anchors[a0];
    const float4 A1 = anchors[a0 + 256];
    const float4 A2 = anchors[a0 + 512];
    const float4 A3 = anchors[a0 + 768];

    // f0 over this block's contiguous 336-float4 slice of preds (no match dep)
    float facc;
    {
        const int pb = L * 336;
        const float4 v0 = preds4[pb + tid];
        facc = (f0(v0.x) + f0(v0.y)) + (f0(v0.z) + f0(v0.w));
        if (tid < 80) {
            const float4 v1 = preds4[pb + 256 + tid];
            facc += (f0(v1.x) + f0(v1.y)) + (f0(v1.z) + f0(v1.w));
        }
    }
    __syncthreads();

    const float ar0 = (A0.z - A0.x) * (A0.w - A0.y);
    const float ar1 = (A1.z - A1.x) * (A1.w - A1.y);
    const float ar2 = (A2.z - A2.x) * (A2.w - A2.y);
    const float ar3 = (A3.z - A3.x) * (A3.w - A3.y);

    // ---- pass 1: pure straight-line (NO branches) -> deep ds_read pipelining
    unsigned long long m0 = 0ull, m1 = 0ull, m2 = 0ull, m3 = 0ull;
    #pragma unroll 16
    for (int t = 0; t < 64; ++t) {
        const float4 tb = s_t[t];
        const float  sa = s_sa[t];
        {
            const float w = fmaxf(fminf(A0.z, tb.z) - fmaxf(A0.x, tb.x), 0.f);
            const float h = fmaxf(fminf(A0.w, tb.w) - fmaxf(A0.y, tb.y), 0.f);
            const float inter = w * h;
            m0 |= (inter + inter >= (ar0 + sa) - inter) ? (1ull << t) : 0ull;
        }
        {
            const float w = fmaxf(fminf(A1.z, tb.z) - fmaxf(A1.x, tb.x), 0.f);
            const float h = fmaxf(fminf(A1.w, tb.w) - fmaxf(A1.y, tb.y), 0.f);
            const float inter = w * h;
            m1 |= (inter + inter >= (ar1 + sa) - inter) ? (1ull << t) : 0ull;
        }
        {
            const float w = fmaxf(fminf(A2.z, tb.z) - fmaxf(A2.x, tb.x), 0.f);
            const float h = fmaxf(fminf(A2.w, tb.w) - fmaxf(A2.y, tb.y), 0.f);
            const float inter = w * h;
            m2 |= (inter + inter >= (ar2 + sa) - inter) ? (1ull << t) : 0ull;
        }
        {
            const float w = fmaxf(fminf(A3.z, tb.z) - fmaxf(A3.x, tb.x), 0.f);
            const float h = fmaxf(fminf(A3.w, tb.w) - fmaxf(A3.y, tb.y), 0.f);
            const float inter = w * h;
            m3 |= (inter + inter >= (ar3 + sa) - inter) ? (1ull << t) : 0ull;
        }
    }

    // ---- pass 2: walk rare set bits; exact IoU recompute (same fp32 rounding)
    #pragma unroll
    for (int q = 0; q < 4; ++q) {
        unsigned long long m = (q == 0) ? m0 : (q == 1) ? m1 : (q == 2) ? m2 : m3;
        if (m != 0ull) {
            const float4 A  = (q == 0) ? A0 : (q == 1) ? A1 : (q == 2) ? A2 : A3;
            const float  ar = (q == 0) ? ar0 : (q == 1) ? ar1 : (q == 2) ? ar2 : ar3;
            const unsigned int aidx = (unsigned int)(a0 + q * 256);
            float b = 0.f;
            int   bi = -1;
            do {   // ascending t (lowest bit first) -> first-index tie-break
                const int t = __ffsll((unsigned long long)m) - 1;
                m &= m - 1;
                const float4 tb = s_t[t];
                const float  sa = s_sa[t];
                const float w = fmaxf(fminf(A.z, tb.z) - fmaxf(A.x, tb.x), 0.f);
                const float h = fmaxf(fminf(A.w, tb.w) - fmaxf(A.y, tb.y), 0.f);
                const float inter = w * h;
                const float uni = (ar + sa) - inter;
                const float iou = inter / uni;
                if (iou > b) { b = iou; bi = t; }
                atomicMax(&s_tk[t], mk_key(iou, aidx));
            } while (m != 0ull);
            // fire-and-forget flush (no return-value dependence — R9 lesson)
            atomicMax(&akeys[aidx], mk_key(b, (unsigned int)(tbase + bi)));
        }
    }

    for (int o = 32; o > 0; o >>= 1) facc += __shfl_down(facc, o);
    if (lane == 0) s_f[wid] = facc;

    __syncthreads();
    if (tid < 64) {
        const unsigned long long tk = s_tk[tid];
        if (tk != 0ull) atomicMax(&tkeys[tbase + tid], tk);
    }
    if (tid == 0)
        __hip_atomic_store(&f0_part[L], s_f[0] + s_f[1] + s_f[2] + s_f[3],
                           __ATOMIC_RELAXED, __HIP_MEMORY_SCOPE_AGENT);

    // barrier drains vmcnt: this block's key flushes complete before counter bump
    __syncthreads();
    if (tid == 0) {
        __threadfence();
        s_last = (atomicAdd(&done_ac[ac], 1) == TCH - 1);
    }
    __syncthreads();
    if (!s_last) return;
    __builtin_amdgcn_fence(__ATOMIC_ACQUIRE, "agent");   // L1 invalidate

    // ============ PHASE B (96 completers): corrections for 1024 anchors =======
    float acc = 0.f;
    int   cnt = 0;
    #pragma unroll
    for (int j = 0; j < 4; ++j) {
        const int a = a0 + j * 256;
        const unsigned long long k = aload64(&akeys[a]);
        if ((unsigned int)(k >> 32) >= HI_MIN) {
            cnt += 1;
            const int lab = tlabels[0xFFFFFFFFu - (unsigned int)k];
            const float x = preds[a * NC + lab];
            acc += f1(x) - f0(x);
        }
    }
    // fold the 16 f0 slices of this ac (written + fenced before done_ac bumps)
    if (tid < TCH) acc += aloadf(&f0_part[ac + tid * ACH]);

    for (int o = 32; o > 0; o >>= 1) {
        acc += __shfl_down(acc, o);
        cnt += __shfl_down(cnt, o);
    }
    if (lane == 0) { s_a[wid] = acc; s_c[wid] = cnt; }
    __syncthreads();
    if (tid == 0) {
        __hip_atomic_store(&corr_part[ac], s_a[0] + s_a[1] + s_a[2] + s_a[3],
                           __ATOMIC_RELAXED, __HIP_MEMORY_SCOPE_AGENT);
        __hip_atomic_store(&npos_part[ac], s_c[0] + s_c[1] + s_c[2] + s_c[3],
                           __ATOMIC_RELAXED, __HIP_MEMORY_SCOPE_AGENT);
        __threadfence();
        s_fin = (atomicAdd(done2, 1) == ACH - 1);
    }
    __syncthreads();
    if (!s_fin) return;
    __builtin_amdgcn_fence(__ATOMIC_ACQUIRE, "agent");

    // ============ PHASE C (last completer): regression + combine ==============
    double cl = 0.0;
    int    np = 0;
    if (tid < ACH) {
        cl = (double)aloadf(&corr_part[tid]);
        np = aloadi(&npos_part[tid]);
    }
    float s = 0.f, m = 0.f;
    #pragma unroll
    for (int j = 0; j < 4; ++j) {
        const int t = tid + 256 * j;
        const unsigned long long key = aload64(&tkeys[t]);
        if ((unsigned int)(key >> 32) >= HI_MIN) {
            const unsigned int ga = 0xFFFFFFFFu - (unsigned int)key;
            const float4 tb  = tboxes[t];
            const float4 abx = anchors[ga];
            const float4 pb  = bpreds[ga];
            const float bw = tb.z - tb.x, bh = tb.w - tb.y;
            const float bcx = tb.x + 0.5f * bw, bcy = tb.y + 0.5f * bh;
            const float aw = abx.z - abx.x, ah = abx.w - abx.y;
            const float acx = abx.x + 0.5f * aw, acy = abx.y + 0.5f * ah;
            const float tx = (bcx - acx) / aw;
            const float ty = (bcy - acy) / ah;
            const float tw = logf(fmaxf(bw, 1e-8f) / aw);
            const float th = logf(fmaxf(bh, 1e-8f) / ah);
            s += smooth_l1(pb.x - tx) + smooth_l1(pb.y - ty) +
                 smooth_l1(pb.z - tw) + smooth_l1(pb.w - th);
            m += 1.f;
        }
    }
    for (int o = 32; o > 0; o >>= 1) {
        cl += __shfl_down(cl, o);
        np += __shfl_down(np, o);
        s  += __shfl_down(s, o);
        m  += __shfl_down(m, o);
    }
    __syncthreads();
    if (lane == 0) { s_d[wid] = cl; s_i[wid] = np; s_s[wid] = s; s_m[wid] = m; }
    __syncthreads();
    if (tid == 0) {
        const double cls_sum = s_d[0] + s_d[1] + s_d[2] + s_d[3];
        const int    npos    = s_i[0] + s_i[1] + s_i[2] + s_i[3];
        const float  rs      = s_s[0] + s_s[1] + s_s[2] + s_s[3];
        const float  rm      = s_m[0] + s_m[1] + s_m[2] + s_m[3];
        const float cls = (float)(cls_sum / (double)npos);
        const float reg = rs / (fmaxf(rm, 1.f) * 4.f);
        out[0] = cls + reg;
        out[1] = cls;
        out[2] = reg;
    }
}

extern "C" void kernel_launch(void* const* d_in, const int* in_sizes, int n_in,
                              void* d_out, int out_size, void* d_ws, size_t ws_size,
                              hipStream_t stream) {
    const float*  preds   = (const float*)d_in[0];
    const float4* preds4  = (const float4*)d_in[0];
    const float4* bpreds  = (const float4*)d_in[1];
    const float4* anchors = (const float4*)d_in[2];
    const float4* tboxes  = (const float4*)d_in[3];
    const int*    tlabels = (const int*)d_in[4];

    char* ws = (char*)d_ws;
    int*    done2     = (int*)(ws + 0);
    int*    done_ac   = (int*)(ws + 64);
    float*  f0_part   = (float*)(ws + 1024);
    float*  corr_part = (float*)(ws + 8192);
    int*    npos_part = (int*)(ws + 8704);
    unsigned long long* tkeys = (unsigned long long*)(ws + 12288);
    unsigned long long* akeys = (unsigned long long*)(ws + 24576);

    // only the done counters need zeroing (everything else unique-slot/poison-proof)
    hipMemsetAsync(d_ws, 0, 1024, stream);

    k_all<<<dim3(ACH, TCH), 256, 0, stream>>>(
        preds, preds4, tlabels, anchors, tboxes, bpreds,
        akeys, tkeys, f0_part, corr_part, npos_part,
        done_ac, done2, (float*)d_out);
}